// Round 1
// baseline (17676.436 us; speedup 1.0000x reference)
//
#include <hip/hip_runtime.h>
#include <stdint.h>

typedef unsigned short u16;
typedef __attribute__((ext_vector_type(8))) short short8;
typedef __attribute__((ext_vector_type(4))) float f32x4;

#define T_SEQ 512
#define NB 32
#define EMBD 1024
#define HID 512
#define G4 2048
#define NROWS (T_SEQ * NB)  // 16384
#define XPW 4096

static __device__ __forceinline__ u16 f2bf(float x) {
  unsigned u = __float_as_uint(x);
  u += 0x7fffu + ((u >> 16) & 1u);
  return (u16)(u >> 16);
}
static __device__ __forceinline__ float bf2f(u16 b) {
  return __uint_as_float(((unsigned)b) << 16);
}
static __device__ __forceinline__ f32x4 mfma16(short8 a, short8 b, f32x4 c) {
  return __builtin_amdgcn_mfma_f32_16x16x32_bf16(a, b, c, 0, 0, 0);
}

// ---------------- weight prep: bf16 convert, Whh split hi/lo, bias merge ----
__global__ void k_prep(const float* __restrict__ Wih, const float* __restrict__ Whh,
                       const float* __restrict__ bih, const float* __restrict__ bhh,
                       u16* __restrict__ wih_b, u16* __restrict__ whh_hi,
                       u16* __restrict__ whh_lo, float* __restrict__ bcat) {
  size_t stride = (size_t)gridDim.x * blockDim.x;
  size_t i0 = (size_t)blockIdx.x * blockDim.x + threadIdx.x;
  const size_t n_ih = (size_t)2 * 2 * G4 * EMBD;  // [l][d][4H][E]
  for (size_t i = i0; i < n_ih; i += stride) wih_b[i] = f2bf(Wih[i]);
  const size_t n_hh = (size_t)2 * 2 * G4 * HID;   // [l][d][4H][H]
  for (size_t i = i0; i < n_hh; i += stride) {
    float w = Whh[i];
    u16 hi = f2bf(w);
    whh_hi[i] = hi;
    whh_lo[i] = f2bf(w - bf2f(hi));
  }
  for (size_t i = i0; i < 2 * 4096; i += stride) {
    size_t l = i >> 12, col = i & 4095;  // col = d*2048+g
    bcat[i] = bih[l * 4096 + col] + bhh[l * 4096 + col];
  }
}

// ---------------- embedding gather -> bf16 X [T*B, 1024] --------------------
__global__ void k_gather(const int* __restrict__ inp, const float* __restrict__ emb,
                         u16* __restrict__ X) {
  int row = blockIdx.x;           // t*32 + b
  int t = row >> 5, b = row & 31;
  int tok = inp[b * T_SEQ + t];
  const float* src = emb + (size_t)tok * EMBD + threadIdx.x * 4;
  float4 v = *reinterpret_cast<const float4*>(src);
  ushort4 o;
  o.x = f2bf(v.x); o.y = f2bf(v.y); o.z = f2bf(v.z); o.w = f2bf(v.w);
  *reinterpret_cast<ushort4*>(X + (size_t)row * EMBD + threadIdx.x * 4) = o;
}

// ---------------- xp GEMM: C[M,4096] = A[M,1024] @ B[4096,1024]^T + bias ----
#define GBM 128
#define GBN 128
#define GBK 64
__global__ __launch_bounds__(256) void k_gemm(const u16* __restrict__ A,
                                              const u16* __restrict__ B,
                                              const float* __restrict__ bias,
                                              u16* __restrict__ C) {
  __shared__ u16 As[GBM][GBK];
  __shared__ u16 Bs[GBN][GBK];
  const int Kdim = 1024, Ndim = 4096;
  int bm = blockIdx.x, bn = blockIdx.y;
  int tid = threadIdx.x;
  int lane = tid & 63, wave = tid >> 6;
  int wm = wave >> 1, wn = wave & 1;
  int l15 = lane & 15, klo = (lane >> 4) * 8;
  f32x4 acc[4][4] = {};
  for (int k0 = 0; k0 < Kdim; k0 += GBK) {
#pragma unroll
    for (int s = 0; s < 4; s++) {
      int seg = tid + s * 256;
      int r = seg >> 3, cs = (seg & 7) * 8;
      *reinterpret_cast<short8*>(&As[r][cs]) =
          *reinterpret_cast<const short8*>(A + (size_t)(bm * GBM + r) * Kdim + k0 + cs);
      *reinterpret_cast<short8*>(&Bs[r][cs]) =
          *reinterpret_cast<const short8*>(B + (size_t)(bn * GBN + r) * Kdim + k0 + cs);
    }
    __syncthreads();
#pragma unroll
    for (int kk = 0; kk < GBK; kk += 32) {
      short8 af[4], bfb[4];
#pragma unroll
      for (int i = 0; i < 4; i++)
        af[i] = *reinterpret_cast<const short8*>(&As[wm * 64 + i * 16 + l15][kk + klo]);
#pragma unroll
      for (int j = 0; j < 4; j++)
        bfb[j] = *reinterpret_cast<const short8*>(&Bs[wn * 64 + j * 16 + l15][kk + klo]);
#pragma unroll
      for (int i = 0; i < 4; i++)
#pragma unroll
        for (int j = 0; j < 4; j++)
          acc[i][j] = mfma16(af[i], bfb[j], acc[i][j]);
    }
    __syncthreads();
  }
  int lg4 = (lane >> 4) * 4;
#pragma unroll
  for (int i = 0; i < 4; i++) {
#pragma unroll
    for (int j = 0; j < 4; j++) {
      int n = bn * GBN + wn * 64 + j * 16 + l15;
      float bv = bias[n];
#pragma unroll
      for (int r = 0; r < 4; r++) {
        int m = bm * GBM + wm * 64 + i * 16 + lg4 + r;
        C[(size_t)m * Ndim + n] = f2bf(acc[i][j][r] + bv);
      }
    }
  }
}

// ---------------- recurrent layer: 64 WGs (32/dir), spin-synced -------------
// WG (dir, slice): 16 hidden units u0..u0+15, wave w = gate w (i,f,g,o).
// Whh hi/lo fragments register-resident. h split hi/lo; 3-product MFMA.
__global__ __launch_bounds__(256, 1) void k_lstm(const u16* __restrict__ xp,
                                                 const u16* __restrict__ whh_hi,
                                                 const u16* __restrict__ whh_lo,
                                                 u16* __restrict__ Yhi,
                                                 u16* __restrict__ Ylo, int* cnt) {
  int blk = blockIdx.x;
  int dir = blk >> 5, slice = blk & 31;
  int tid = threadIdx.x, wave = tid >> 6, lane = tid & 63;
  int u0 = slice * 16;
  int l15 = lane & 15, lg = lane >> 4;
  int klo = lg * 8;
  short8 wh[16], wl[16];
  {
    size_t wroff = ((size_t)dir * G4 + wave * HID + u0 + l15) * HID + klo;
#pragma unroll
    for (int kt = 0; kt < 16; kt++) {
      wh[kt] = *reinterpret_cast<const short8*>(whh_hi + wroff + kt * 32);
      wl[kt] = *reinterpret_cast<const short8*>(whh_lo + wroff + kt * 32);
    }
  }
  __shared__ float gx[4][32][16];  // [gate][b][uu]
  float c0 = 0.f, c1 = 0.f;
  int* mycnt = cnt + dir * T_SEQ;
  int xcol = dir * 2048 + wave * HID + u0 + l15;
  for (int s = 0; s < T_SEQ; s++) {
    int trow = dir ? (T_SEQ - 1 - s) : s;
    f32x4 z = {0.f, 0.f, 0.f, 0.f};
    f32x4 acc0 = z, acc1 = z, acc2 = z, acc3 = z, acc4 = z, acc5 = z;
    {  // prefetch xp slice into acc (issues before the spin)
      const u16* xb = xp + (size_t)trow * NB * XPW + xcol;
#pragma unroll
      for (int r = 0; r < 4; r++) {
        acc0[r] = bf2f(xb[(size_t)(4 * lg + r) * XPW]);
        acc1[r] = bf2f(xb[(size_t)(16 + 4 * lg + r) * XPW]);
      }
    }
    if (s > 0) {
      if (tid == 0) {
        while (__hip_atomic_load(mycnt + s - 1, __ATOMIC_ACQUIRE,
                                 __HIP_MEMORY_SCOPE_AGENT) < 32)
          __builtin_amdgcn_s_sleep(1);
      }
      __syncthreads();
      int prow = dir ? (T_SEQ - s) : (s - 1);
      const u16* yb  = Yhi + ((size_t)prow * NB + l15) * 1024 + dir * HID + klo;
      const u16* ybl = Ylo + ((size_t)prow * NB + l15) * 1024 + dir * HID + klo;
#pragma unroll
      for (int kt = 0; kt < 16; kt++) {
        short8 ah0 = *reinterpret_cast<const short8*>(yb + kt * 32);
        short8 ah1 = *reinterpret_cast<const short8*>(yb + 16 * 1024 + kt * 32);
        short8 al0 = *reinterpret_cast<const short8*>(ybl + kt * 32);
        short8 al1 = *reinterpret_cast<const short8*>(ybl + 16 * 1024 + kt * 32);
        acc0 = mfma16(ah0, wh[kt], acc0);
        acc1 = mfma16(ah1, wh[kt], acc1);
        acc2 = mfma16(al0, wh[kt], acc2);
        acc3 = mfma16(al1, wh[kt], acc3);
        acc4 = mfma16(ah0, wl[kt], acc4);
        acc5 = mfma16(ah1, wl[kt], acc5);
      }
      acc0 += acc2; acc0 += acc4;
      acc1 += acc3; acc1 += acc5;
    }
#pragma unroll
    for (int r = 0; r < 4; r++) {
      gx[wave][4 * lg + r][l15] = acc0[r];
      gx[wave][16 + 4 * lg + r][l15] = acc1[r];
    }
    __syncthreads();
#pragma unroll
    for (int j = 0; j < 2; j++) {
      int p = tid + 256 * j;
      int uu = p & 15, b = p >> 4;
      float gi = gx[0][b][uu], gf = gx[1][b][uu], gg = gx[2][b][uu], go = gx[3][b][uu];
      float iv = 1.f / (1.f + __expf(-gi));
      float fv = 1.f / (1.f + __expf(-gf));
      float gv = tanhf(gg);
      float ov = 1.f / (1.f + __expf(-go));
      float& c = j ? c1 : c0;
      c = fv * c + iv * gv;
      float h = ov * tanhf(c);
      u16 hhv = f2bf(h);
      size_t yo = ((size_t)trow * NB + b) * 1024 + dir * HID + u0 + uu;
      Yhi[yo] = hhv;
      Ylo[yo] = f2bf(h - bf2f(hhv));
    }
    __threadfence();
    __syncthreads();
    if (tid == 0)
      __hip_atomic_fetch_add(mycnt + s, 1, __ATOMIC_RELEASE, __HIP_MEMORY_SCOPE_AGENT);
  }
}

// ---------------- final pooled dot ------------------------------------------
__global__ void k_out(const u16* __restrict__ Yhi, const u16* __restrict__ Ylo,
                      const float* __restrict__ wout, const float* __restrict__ bout,
                      float* __restrict__ out) {
  int b = blockIdx.x;
  __shared__ float red[256];
  float s = 0.f;
  for (int c = threadIdx.x; c < 1024; c += 256) {
    size_t row = (c < 512) ? ((size_t)(T_SEQ - 1) * NB + b) : (size_t)b;
    float h = bf2f(Yhi[row * 1024 + c]) + bf2f(Ylo[row * 1024 + c]);
    s += h * wout[c];
  }
  red[threadIdx.x] = s;
  __syncthreads();
  for (int st = 128; st > 0; st >>= 1) {
    if (threadIdx.x < st) red[threadIdx.x] += red[threadIdx.x + st];
    __syncthreads();
  }
  if (threadIdx.x == 0) out[b] = red[0] + bout[0];
}

extern "C" void kernel_launch(void* const* d_in, const int* in_sizes, int n_in,
                              void* d_out, int out_size, void* d_ws, size_t ws_size,
                              hipStream_t stream) {
  const int*   inp  = (const int*)d_in[0];
  const float* emb  = (const float*)d_in[1];
  const float* Wih  = (const float*)d_in[2];
  const float* Whh  = (const float*)d_in[3];
  const float* bih  = (const float*)d_in[4];
  const float* bhh  = (const float*)d_in[5];
  const float* Wout = (const float*)d_in[6];
  const float* bout = (const float*)d_in[7];
  float* out = (float*)d_out;
  char* ws = (char*)d_ws;

  const size_t SZ_XP  = (size_t)NROWS * XPW * 2;
  const size_t SZ_Y   = (size_t)NROWS * 1024 * 2;
  const size_t SZ_WIH = (size_t)2 * 4096 * 1024 * 2;
  const size_t SZ_WHH = (size_t)2 * 2 * G4 * HID * 2;
  size_t off = 0;
  auto alloc = [&](size_t n) { size_t o = off; off += (n + 255) & ~(size_t)255; return o; };
  size_t o_xp   = alloc(SZ_XP);
  size_t o_y1h  = alloc(SZ_Y);
  size_t o_y1l  = alloc(SZ_Y);
  size_t o_y2h  = alloc(SZ_Y);   // aliased as X1 (embedding) before layer 2
  size_t o_y2l  = alloc(SZ_Y);
  size_t o_wih  = alloc(SZ_WIH);
  size_t o_whhh = alloc(SZ_WHH);
  size_t o_whhl = alloc(SZ_WHH);
  size_t o_bc   = alloc(2 * 4096 * sizeof(float));
  size_t o_cnt  = alloc(2 * 2 * T_SEQ * sizeof(int));
  if (ws_size < off) return;  // workspace too small: bail (bench will flag)

  u16* xp   = (u16*)(ws + o_xp);
  u16* y1h  = (u16*)(ws + o_y1h);
  u16* y1l  = (u16*)(ws + o_y1l);
  u16* y2h  = (u16*)(ws + o_y2h);
  u16* y2l  = (u16*)(ws + o_y2l);
  u16* x1   = y2h;  // alias: dead before k_lstm layer-2 writes y2h
  u16* wihb = (u16*)(ws + o_wih);
  u16* whhh = (u16*)(ws + o_whhh);
  u16* whhl = (u16*)(ws + o_whhl);
  float* bc = (float*)(ws + o_bc);
  int* cnt  = (int*)(ws + o_cnt);

  hipMemsetAsync(cnt, 0, 2 * 2 * T_SEQ * sizeof(int), stream);
  k_prep<<<4096, 256, 0, stream>>>(Wih, Whh, bih, bhh, wihb, whhh, whhl, bc);
  k_gather<<<NROWS, 256, 0, stream>>>(inp, emb, x1);
  k_gemm<<<dim3(NROWS / GBM, XPW / GBN), 256, 0, stream>>>(x1, wihb, bc, xp);
  k_lstm<<<64, 256, 0, stream>>>(xp, whhh, whhl, y1h, y1l, cnt);
  k_gemm<<<dim3(NROWS / GBM, XPW / GBN), 256, 0, stream>>>(
      y1h, wihb + (size_t)4096 * 1024, bc + 4096, xp);
  k_lstm<<<64, 256, 0, stream>>>(xp, whhh + (size_t)2 * G4 * HID,
                                 whhl + (size_t)2 * G4 * HID, y2h, y2l,
                                 cnt + 2 * T_SEQ);
  k_out<<<NB, 256, 0, stream>>>(y2h, y2l, Wout, bout, out);
}